// Round 2
// baseline (183.307 us; speedup 1.0000x reference)
//
#include <hip/hip_runtime.h>

// GraphConv (DGL norm='both', implicit self-loop), N=100000, D=64, E=1250000.
// R13 (resubmit — previous round hit GPUAcquisitionTimeout, never measured).
// Theory: partition_kernel was ~30-40us — 153 blocks (60% CU util, 1 resident
// block/CU) each doing 2 passes x (4 LDS atomics + 2 scattered stores)/edge
// for BOTH A and B sides. The whole B side existed only to compute out-degs.
//   1) streamB/curB dropped; outdeg[n] via 1 global atomicAdd/edge in pass 1
//      (fallback path proved this cheap: ~12.5 hits/counter, L2-resident).
//   2) EPB 8192 -> 2442: exactly 512 blocks ~= 2/CU, balanced, per-block
//      serial atomic work cut ~6x.
//   3) convertB -> pure streaming float4/ushort4 convert (no stream read,
//      no LDS histogram), ~6us at BW.
// sortgather untouched (R9-proven; near its random-gather fabric floor:
// 1.25M random 128B featb lines ~= 160MB from L2/L3).
// Pipeline: memset(curA+outdeg, 402KB) -> partition -> convert -> sortgather.

#define GC_D 64
#define PSIZE 196     // nodes per partition: ceil(100000/511); 511 ~ 2*256 CUs
#define SCAP 3072     // stream slots per partition (mean 2450, +12 sigma)
#define EPB 2442      // edges per block: ceil(1250000/512) -> 512 blocks ~ 2/CU
#define MAXPART 512
#define GC_CAP 64     // fallback-A bucket capacity

// ---------------- main-path kernels ----------------

__global__ __launch_bounds__(512) void partition_kernel(
        const int* __restrict__ src,
        const int* __restrict__ dst,
        int* __restrict__ curA,                 // [nPart] cursors (dst-keyed)
        int* __restrict__ outdeg,               // [n] global out-degrees
        int* __restrict__ streamA,              // [nPart*SCAP] s | (d%PSIZE)<<17
        int e, int nPart) {
    __shared__ int histA[MAXPART], baseA[MAXPART], lcurA[MAXPART];
    int t = threadIdx.x;
    for (int i = t; i < nPart; i += 512) { histA[i] = 0; lcurA[i] = 0; }
    __syncthreads();
    int lo = blockIdx.x * EPB;
    int hi = min(lo + EPB, e);
    for (int i = lo + t; i < hi; i += 512) {
        int s = src[i], d = dst[i];
        atomicAdd(&histA[d / PSIZE], 1);
        atomicAdd(&outdeg[s], 1);
    }
    __syncthreads();
    for (int i = t; i < nPart; i += 512) {
        int hA = histA[i];
        baseA[i] = hA ? atomicAdd(&curA[i], hA) : 0;
    }
    __syncthreads();
    for (int i = lo + t; i < hi; i += 512) {
        int s = src[i], d = dst[i];
        int pA = d / PSIZE;                      // compile-time magic div
        int posA = baseA[pA] + atomicAdd(&lcurA[pA], 1);
        if (posA < SCAP) streamA[pA * SCAP + posA] = s | ((d - pA * PSIZE) << 17);
    }
}

// Pure streaming premultiplied bf16 convert. One thread per float4 (16B in,
// 8B out, fully coalesced). Row n is the zero pad target for gather.
__device__ __forceinline__ unsigned short to_bf16_rne(float v) {
    unsigned b = __float_as_uint(v);
    b = (b + 0x7FFFu + ((b >> 16) & 1u)) >> 16;   // RNE to bf16
    return (unsigned short)b;
}

__global__ __launch_bounds__(256) void convert_kernel(
        const float* __restrict__ feat,
        const int* __restrict__ outdeg,
        unsigned short* __restrict__ featb,
        int n) {
    int i = blockIdx.x * 256 + threadIdx.x;   // float4 / ushort4 index
    int row = i >> 4;                          // 16 float4s per 64-wide row
    if (row > n) return;
    if (row == n) {
        ushort4 z; z.x = 0; z.y = 0; z.z = 0; z.w = 0;
        *(ushort4*)(featb + (size_t)i * 4) = z;
        return;
    }
    float nl = rsqrtf(fmaxf((float)outdeg[row], 1.0f) + 1.0f);
    float4 v = *(const float4*)(feat + (size_t)i * 4);
    ushort4 r;
    r.x = to_bf16_rne(v.x * nl);
    r.y = to_bf16_rne(v.y * nl);
    r.z = to_bf16_rne(v.z * nl);
    r.w = to_bf16_rne(v.w * nl);
    *(ushort4*)(featb + (size_t)i * 4) = r;
}

// One 1024-thread block per partition (~2 blocks/CU, balanced). Drain streamA
// into LDS, LDS counting sort into lperm, 16 waves gather one node at a time
// (R9's proven pattern: compiler overlaps independent r-iterations).
__global__ __launch_bounds__(1024) void sortgather_kernel(
        const int* __restrict__ curA,
        const int* __restrict__ streamA,
        const float* __restrict__ feat,
        const unsigned short* __restrict__ featb,
        float* __restrict__ out,
        int n) {
    __shared__ int sAl[SCAP];       // 12 KB staged stream
    __shared__ int lperm[SCAP];     // 12 KB sorted src ids
    __shared__ int lcnt[256], loff[256], lcur[256];
    int p = blockIdx.x, t = threadIdx.x;
    if (t < 256) lcnt[t] = 0;
    __syncthreads();
    int cA = min(curA[p], SCAP);
    const int* sA = streamA + (size_t)p * SCAP;
    for (int i = t; i < cA; i += 1024) {
        int v = sA[i];
        sAl[i] = v;
        atomicAdd(&lcnt[(v >> 17) & 255], 1);
    }
    __syncthreads();
    // exclusive scan of 256 bins (Hillis-Steele on first 256 threads)
    if (t < 256) loff[t] = lcnt[t];
    __syncthreads();
    for (int off = 1; off < 256; off <<= 1) {
        int a = (t < 256 && t >= off) ? loff[t - off] : 0;
        __syncthreads();
        if (t < 256) loff[t] += a;
        __syncthreads();
    }
    if (t < 256) { loff[t] -= lcnt[t]; lcur[t] = 0; }   // exclusive
    __syncthreads();
    for (int i = t; i < cA; i += 1024) {
        int v = sAl[i];
        int bin = (v >> 17) & 255;
        int pos = loff[bin] + atomicAdd(&lcur[bin], 1);
        lperm[pos] = v & 0x1FFFF;
    }
    __syncthreads();
    // gather: wave w handles nodes w, w+16, ...
    int wave = t >> 6, lane = t & 63;
    int half = lane >> 5;      // 0: even edges, 1: odd edges
    int c = lane & 31;         // feature-pair index
    int g = p * PSIZE;
    for (int r = wave; r < PSIZE; r += 16) {
        int node = g + r;
        if (node >= n) break;
        int deg = lcnt[r];
        int off = loff[r];
        float acc0 = 0.0f, acc1 = 0.0f;
        for (int base = 0; base < deg; base += 64) {
            int m = min(deg - base, 64);
            int s_l = (lane < m) ? lperm[off + base + lane] : n;
            int m16 = (m + 15) & ~15;
            for (int j = 0; j < m16; j += 16) {
#pragma unroll
                for (int k = 0; k < 8; ++k) {
                    int s = __shfl(s_l, j + 2 * k + half);
                    unsigned u = *(const unsigned*)(featb + (size_t)s * GC_D + 2 * c);
                    acc0 += __uint_as_float(u << 16);
                    acc1 += __uint_as_float(u & 0xFFFF0000u);
                }
            }
        }
        acc0 += __shfl_xor(acc0, 32);
        acc1 += __shfl_xor(acc1, 32);
        if (half == 0) {
            float nr = rsqrtf(fmaxf((float)deg, 1.0f) + 1.0f);
            const float2 self = *(const float2*)(feat + (size_t)node * GC_D + 2 * c);
            float2 rr;
            rr.x = (self.x + acc0) * nr;
            rr.y = (self.y + acc1) * nr;
            *(float2*)(out + (size_t)node * GC_D + 2 * c) = rr;
        }
    }
}

// ---------------- fallback A (atomic-bucket path, R4-style) ----------------

__global__ void zero_int_kernel(int* __restrict__ p, int n) {
    int i = blockIdx.x * blockDim.x + threadIdx.x;
    if (i < n) p[i] = 0;
}

__global__ void bucket_hist_kernel(const int* __restrict__ src,
                                   const int* __restrict__ dst,
                                   int* __restrict__ cnt,
                                   int* __restrict__ outdeg,
                                   int* __restrict__ bucket,
                                   int e) {
    int i = blockIdx.x * blockDim.x + threadIdx.x;
    if (i < e) {
        int s = src[i];
        int d = dst[i];
        atomicAdd(&outdeg[s], 1);
        int pos = atomicAdd(&cnt[d], 1);
        if (pos < GC_CAP) bucket[d * GC_CAP + pos] = s;
    }
}

__global__ __launch_bounds__(256) void gather_bf16_kernel(
        const float* __restrict__ feat,
        const unsigned short* __restrict__ featb,
        const int* __restrict__ bucket,
        const int* __restrict__ cnt,
        float* __restrict__ out,
        int n) {
    int wid = (blockIdx.x * blockDim.x + threadIdx.x) >> 6;
    int lane = threadIdx.x & 63;
    if (wid >= n) return;
    int deg = cnt[wid];
    int s_raw = bucket[wid * GC_CAP + lane];
    int m = min(deg, GC_CAP);
    int s_l = (lane < m) ? s_raw : n;
    int half = lane >> 5;
    int c = lane & 31;
    float acc0 = 0.0f, acc1 = 0.0f;
    int m16 = (m + 15) & ~15;
    for (int j = 0; j < m16; j += 16) {
#pragma unroll
        for (int k = 0; k < 8; ++k) {
            int s = __shfl(s_l, j + 2 * k + half);
            unsigned u = *(const unsigned*)(featb + (size_t)s * GC_D + 2 * c);
            acc0 += __uint_as_float(u << 16);
            acc1 += __uint_as_float(u & 0xFFFF0000u);
        }
    }
    acc0 += __shfl_xor(acc0, 32);
    acc1 += __shfl_xor(acc1, 32);
    if (half == 0) {
        float nr = rsqrtf(fmaxf((float)deg, 1.0f) + 1.0f);
        const float2 self = *(const float2*)(feat + (size_t)wid * GC_D + 2 * c);
        float2 r;
        r.x = (self.x + acc0) * nr;
        r.y = (self.y + acc1) * nr;
        *(float2*)(out + (size_t)wid * GC_D + 2 * c) = r;
    }
}

// ---------------- launch ----------------

extern "C" void kernel_launch(void* const* d_in, const int* in_sizes, int n_in,
                              void* d_out, int out_size, void* d_ws, size_t ws_size,
                              hipStream_t stream) {
    const float* feat = (const float*)d_in[0];
    const int*   src  = (const int*)d_in[1];
    const int*   dst  = (const int*)d_in[2];
    float* out = (float*)d_out;

    const int n = in_sizes[0] / GC_D;   // 100000
    const int e = in_sizes[1];          // 1250000
    const int nPart = (n + PSIZE - 1) / PSIZE;    // 511 for n=100000

    // Main ws layout (int units): curA[nPart] outdeg[n] pad32 ->
    //   streamA[nPart*SCAP] -> featb[(n+1)*64 u16]
    size_t featb_ints = ((size_t)(n + 1) * GC_D + 1) / 2;
    size_t o = (size_t)nPart + (size_t)n;
    o = (o + 31) & ~(size_t)31;          // 128B-align streamA (and featb below)
    size_t streamA_o = o;  o += (size_t)nPart * SCAP;
    size_t featb_o = o;    o += featb_ints;
    size_t need_main = o * sizeof(int);

    size_t featb_bytes = (size_t)(n + 1) * GC_D * sizeof(unsigned short);
    size_t need_bf16 = ((size_t)2 * n + (size_t)n * GC_CAP) * sizeof(int) + featb_bytes;

    bool main_ok = (ws_size >= need_main) && nPart <= MAXPART && n <= 131071;

    if (main_ok) {
        int* ws = (int*)d_ws;
        int* curA = ws;
        int* outdeg = ws + nPart;
        int* streamA = ws + streamA_o;
        unsigned short* featb = (unsigned short*)(ws + featb_o);

        hipMemsetAsync(curA, 0, ((size_t)nPart + n) * sizeof(int), stream);
        partition_kernel<<<(e + EPB - 1) / EPB, 512, 0, stream>>>(
            src, dst, curA, outdeg, streamA, e, nPart);
        int conv_threads = (n + 1) * 16;     // one thread per float4
        convert_kernel<<<(conv_threads + 255) / 256, 256, 0, stream>>>(
            feat, outdeg, featb, n);
        sortgather_kernel<<<nPart, 1024, 0, stream>>>(curA, streamA, feat, featb,
                                                      out, n);
    } else if (ws_size >= need_bf16) {
        int* cnt    = (int*)d_ws;
        int* outdeg = cnt + n;
        int* bucket = outdeg + n;
        unsigned short* featb = (unsigned short*)(bucket + (size_t)n * GC_CAP);

        zero_int_kernel<<<(2 * n + 255) / 256, 256, 0, stream>>>(cnt, 2 * n);
        bucket_hist_kernel<<<(e + 255) / 256, 256, 0, stream>>>(src, dst, cnt,
                                                                outdeg, bucket, e);
        int conv_threads = (n + 1) * 16;
        convert_kernel<<<(conv_threads + 255) / 256, 256, 0, stream>>>(
            feat, outdeg, featb, n);
        long long total = (long long)n * GC_D;
        gather_bf16_kernel<<<(int)((total + 255) / 256), 256, 0, stream>>>(
            feat, featb, bucket, cnt, out, n);
    }
}

// Round 3
// 181.051 us; speedup vs baseline: 1.0125x; 1.0125x over previous
//
#include <hip/hip_runtime.h>

// GraphConv (DGL norm='both', implicit self-loop), N=100000, D=64, E=1250000.
// R14: post-mortem of R13 (183us, partition 65.7us, WRITE_SIZE 52.7MB):
// 512 blocks regressed partition two ways, both prop. to block count:
//   (a) curA return-atomic depth 153->512 per counter (barrier-gated),
//   (b) streamA write runs 16 dwords -> 4.8 dwords => ~10x partial-line
//       write amplification (52.7MB for 5MB payload).
// R14 restores EPB=8192 (153 blocks, the R12-proven grid) while KEEPING the
// orthogonal B-side elimination (no streamB scattered byte-stores, no curB
// reservations, no convertB LDS hist; outdeg via 1.25M fire-and-forget
// global atomics over 100K addrs + pure streaming float4->ushort4 convert).
// Clean A/B: if partition still >=55us at 153 blocks, per-edge global
// atomics are the cost -> revert to streamB next round.
// Pipeline: memset(curA+outdeg, 402KB) -> partition -> convert -> sortgather.

#define GC_D 64
#define PSIZE 196     // nodes per partition: ceil(100000/511); 511 ~ 2*256 CUs
#define SCAP 3072     // stream slots per partition (mean 2450, +12 sigma)
#define EPB 8192      // edges per block: 153 blocks (R12-proven; long runs)
#define MAXPART 512
#define GC_CAP 64     // fallback-A bucket capacity

// ---------------- main-path kernels ----------------

__global__ __launch_bounds__(512) void partition_kernel(
        const int* __restrict__ src,
        const int* __restrict__ dst,
        int* __restrict__ curA,                 // [nPart] cursors (dst-keyed)
        int* __restrict__ outdeg,               // [n] global out-degrees
        int* __restrict__ streamA,              // [nPart*SCAP] s | (d%PSIZE)<<17
        int e, int nPart) {
    __shared__ int histA[MAXPART], baseA[MAXPART], lcurA[MAXPART];
    int t = threadIdx.x;
    for (int i = t; i < nPart; i += 512) { histA[i] = 0; lcurA[i] = 0; }
    __syncthreads();
    int lo = blockIdx.x * EPB;
    int hi = min(lo + EPB, e);
    for (int i = lo + t; i < hi; i += 512) {
        int s = src[i], d = dst[i];
        atomicAdd(&histA[d / PSIZE], 1);
        atomicAdd(&outdeg[s], 1);               // fire-and-forget, 100K addrs
    }
    __syncthreads();
    for (int i = t; i < nPart; i += 512) {
        int hA = histA[i];
        baseA[i] = hA ? atomicAdd(&curA[i], hA) : 0;   // 153-deep per counter
    }
    __syncthreads();
    for (int i = lo + t; i < hi; i += 512) {
        int s = src[i], d = dst[i];
        int pA = d / PSIZE;                      // compile-time magic div
        int posA = baseA[pA] + atomicAdd(&lcurA[pA], 1);
        if (posA < SCAP) streamA[pA * SCAP + posA] = s | ((d - pA * PSIZE) << 17);
    }
}

// Pure streaming premultiplied bf16 convert. One thread per float4 (16B in,
// 8B out, fully coalesced). Row n is the zero pad target for gather.
__device__ __forceinline__ unsigned short to_bf16_rne(float v) {
    unsigned b = __float_as_uint(v);
    b = (b + 0x7FFFu + ((b >> 16) & 1u)) >> 16;   // RNE to bf16
    return (unsigned short)b;
}

__global__ __launch_bounds__(256) void convert_kernel(
        const float* __restrict__ feat,
        const int* __restrict__ outdeg,
        unsigned short* __restrict__ featb,
        int n) {
    int i = blockIdx.x * 256 + threadIdx.x;   // float4 / ushort4 index
    int row = i >> 4;                          // 16 float4s per 64-wide row
    if (row > n) return;
    if (row == n) {
        ushort4 z; z.x = 0; z.y = 0; z.z = 0; z.w = 0;
        *(ushort4*)(featb + (size_t)i * 4) = z;
        return;
    }
    float nl = rsqrtf(fmaxf((float)outdeg[row], 1.0f) + 1.0f);
    float4 v = *(const float4*)(feat + (size_t)i * 4);
    ushort4 r;
    r.x = to_bf16_rne(v.x * nl);
    r.y = to_bf16_rne(v.y * nl);
    r.z = to_bf16_rne(v.z * nl);
    r.w = to_bf16_rne(v.w * nl);
    *(ushort4*)(featb + (size_t)i * 4) = r;
}

// One 1024-thread block per partition (~2 blocks/CU, balanced). Drain streamA
// into LDS, LDS counting sort into lperm, 16 waves gather one node at a time
// (R9's proven pattern: compiler overlaps independent r-iterations).
__global__ __launch_bounds__(1024) void sortgather_kernel(
        const int* __restrict__ curA,
        const int* __restrict__ streamA,
        const float* __restrict__ feat,
        const unsigned short* __restrict__ featb,
        float* __restrict__ out,
        int n) {
    __shared__ int sAl[SCAP];       // 12 KB staged stream
    __shared__ int lperm[SCAP];     // 12 KB sorted src ids
    __shared__ int lcnt[256], loff[256], lcur[256];
    int p = blockIdx.x, t = threadIdx.x;
    if (t < 256) lcnt[t] = 0;
    __syncthreads();
    int cA = min(curA[p], SCAP);
    const int* sA = streamA + (size_t)p * SCAP;
    for (int i = t; i < cA; i += 1024) {
        int v = sA[i];
        sAl[i] = v;
        atomicAdd(&lcnt[(v >> 17) & 255], 1);
    }
    __syncthreads();
    // exclusive scan of 256 bins (Hillis-Steele on first 256 threads)
    if (t < 256) loff[t] = lcnt[t];
    __syncthreads();
    for (int off = 1; off < 256; off <<= 1) {
        int a = (t < 256 && t >= off) ? loff[t - off] : 0;
        __syncthreads();
        if (t < 256) loff[t] += a;
        __syncthreads();
    }
    if (t < 256) { loff[t] -= lcnt[t]; lcur[t] = 0; }   // exclusive
    __syncthreads();
    for (int i = t; i < cA; i += 1024) {
        int v = sAl[i];
        int bin = (v >> 17) & 255;
        int pos = loff[bin] + atomicAdd(&lcur[bin], 1);
        lperm[pos] = v & 0x1FFFF;
    }
    __syncthreads();
    // gather: wave w handles nodes w, w+16, ...
    int wave = t >> 6, lane = t & 63;
    int half = lane >> 5;      // 0: even edges, 1: odd edges
    int c = lane & 31;         // feature-pair index
    int g = p * PSIZE;
    for (int r = wave; r < PSIZE; r += 16) {
        int node = g + r;
        if (node >= n) break;
        int deg = lcnt[r];
        int off = loff[r];
        float acc0 = 0.0f, acc1 = 0.0f;
        for (int base = 0; base < deg; base += 64) {
            int m = min(deg - base, 64);
            int s_l = (lane < m) ? lperm[off + base + lane] : n;
            int m16 = (m + 15) & ~15;
            for (int j = 0; j < m16; j += 16) {
#pragma unroll
                for (int k = 0; k < 8; ++k) {
                    int s = __shfl(s_l, j + 2 * k + half);
                    unsigned u = *(const unsigned*)(featb + (size_t)s * GC_D + 2 * c);
                    acc0 += __uint_as_float(u << 16);
                    acc1 += __uint_as_float(u & 0xFFFF0000u);
                }
            }
        }
        acc0 += __shfl_xor(acc0, 32);
        acc1 += __shfl_xor(acc1, 32);
        if (half == 0) {
            float nr = rsqrtf(fmaxf((float)deg, 1.0f) + 1.0f);
            const float2 self = *(const float2*)(feat + (size_t)node * GC_D + 2 * c);
            float2 rr;
            rr.x = (self.x + acc0) * nr;
            rr.y = (self.y + acc1) * nr;
            *(float2*)(out + (size_t)node * GC_D + 2 * c) = rr;
        }
    }
}

// ---------------- fallback A (atomic-bucket path, R4-style) ----------------

__global__ void zero_int_kernel(int* __restrict__ p, int n) {
    int i = blockIdx.x * blockDim.x + threadIdx.x;
    if (i < n) p[i] = 0;
}

__global__ void bucket_hist_kernel(const int* __restrict__ src,
                                   const int* __restrict__ dst,
                                   int* __restrict__ cnt,
                                   int* __restrict__ outdeg,
                                   int* __restrict__ bucket,
                                   int e) {
    int i = blockIdx.x * blockDim.x + threadIdx.x;
    if (i < e) {
        int s = src[i];
        int d = dst[i];
        atomicAdd(&outdeg[s], 1);
        int pos = atomicAdd(&cnt[d], 1);
        if (pos < GC_CAP) bucket[d * GC_CAP + pos] = s;
    }
}

__global__ __launch_bounds__(256) void gather_bf16_kernel(
        const float* __restrict__ feat,
        const unsigned short* __restrict__ featb,
        const int* __restrict__ bucket,
        const int* __restrict__ cnt,
        float* __restrict__ out,
        int n) {
    int wid = (blockIdx.x * blockDim.x + threadIdx.x) >> 6;
    int lane = threadIdx.x & 63;
    if (wid >= n) return;
    int deg = cnt[wid];
    int s_raw = bucket[wid * GC_CAP + lane];
    int m = min(deg, GC_CAP);
    int s_l = (lane < m) ? s_raw : n;
    int half = lane >> 5;
    int c = lane & 31;
    float acc0 = 0.0f, acc1 = 0.0f;
    int m16 = (m + 15) & ~15;
    for (int j = 0; j < m16; j += 16) {
#pragma unroll
        for (int k = 0; k < 8; ++k) {
            int s = __shfl(s_l, j + 2 * k + half);
            unsigned u = *(const unsigned*)(featb + (size_t)s * GC_D + 2 * c);
            acc0 += __uint_as_float(u << 16);
            acc1 += __uint_as_float(u & 0xFFFF0000u);
        }
    }
    acc0 += __shfl_xor(acc0, 32);
    acc1 += __shfl_xor(acc1, 32);
    if (half == 0) {
        float nr = rsqrtf(fmaxf((float)deg, 1.0f) + 1.0f);
        const float2 self = *(const float2*)(feat + (size_t)wid * GC_D + 2 * c);
        float2 r;
        r.x = (self.x + acc0) * nr;
        r.y = (self.y + acc1) * nr;
        *(float2*)(out + (size_t)wid * GC_D + 2 * c) = r;
    }
}

// ---------------- launch ----------------

extern "C" void kernel_launch(void* const* d_in, const int* in_sizes, int n_in,
                              void* d_out, int out_size, void* d_ws, size_t ws_size,
                              hipStream_t stream) {
    const float* feat = (const float*)d_in[0];
    const int*   src  = (const int*)d_in[1];
    const int*   dst  = (const int*)d_in[2];
    float* out = (float*)d_out;

    const int n = in_sizes[0] / GC_D;   // 100000
    const int e = in_sizes[1];          // 1250000
    const int nPart = (n + PSIZE - 1) / PSIZE;    // 511 for n=100000

    // Main ws layout (int units): curA[nPart] outdeg[n] pad32 ->
    //   streamA[nPart*SCAP] -> featb[(n+1)*64 u16]
    size_t featb_ints = ((size_t)(n + 1) * GC_D + 1) / 2;
    size_t o = (size_t)nPart + (size_t)n;
    o = (o + 31) & ~(size_t)31;          // 128B-align streamA (and featb below)
    size_t streamA_o = o;  o += (size_t)nPart * SCAP;
    size_t featb_o = o;    o += featb_ints;
    size_t need_main = o * sizeof(int);

    size_t featb_bytes = (size_t)(n + 1) * GC_D * sizeof(unsigned short);
    size_t need_bf16 = ((size_t)2 * n + (size_t)n * GC_CAP) * sizeof(int) + featb_bytes;

    bool main_ok = (ws_size >= need_main) && nPart <= MAXPART && n <= 131071;

    if (main_ok) {
        int* ws = (int*)d_ws;
        int* curA = ws;
        int* outdeg = ws + nPart;
        int* streamA = ws + streamA_o;
        unsigned short* featb = (unsigned short*)(ws + featb_o);

        hipMemsetAsync(curA, 0, ((size_t)nPart + n) * sizeof(int), stream);
        partition_kernel<<<(e + EPB - 1) / EPB, 512, 0, stream>>>(
            src, dst, curA, outdeg, streamA, e, nPart);
        int conv_threads = (n + 1) * 16;     // one thread per float4
        convert_kernel<<<(conv_threads + 255) / 256, 256, 0, stream>>>(
            feat, outdeg, featb, n);
        sortgather_kernel<<<nPart, 1024, 0, stream>>>(curA, streamA, feat, featb,
                                                      out, n);
    } else if (ws_size >= need_bf16) {
        int* cnt    = (int*)d_ws;
        int* outdeg = cnt + n;
        int* bucket = outdeg + n;
        unsigned short* featb = (unsigned short*)(bucket + (size_t)n * GC_CAP);

        zero_int_kernel<<<(2 * n + 255) / 256, 256, 0, stream>>>(cnt, 2 * n);
        bucket_hist_kernel<<<(e + 255) / 256, 256, 0, stream>>>(src, dst, cnt,
                                                                outdeg, bucket, e);
        int conv_threads = (n + 1) * 16;
        convert_kernel<<<(conv_threads + 255) / 256, 256, 0, stream>>>(
            feat, outdeg, featb, n);
        long long total = (long long)n * GC_D;
        gather_bf16_kernel<<<(int)((total + 255) / 256), 256, 0, stream>>>(
            feat, featb, bucket, cnt, out, n);
    }
}

// Round 5
// 155.810 us; speedup vs baseline: 1.1765x; 1.1620x over previous
//
#include <hip/hip_runtime.h>

// GraphConv (DGL norm='both', implicit self-loop), N=100000, D=64, E=1250000.
// R15 (resubmit — round 4 hit GPUAcquisitionTimeout, never measured).
// R13/R14 A/B isolated the regression: 1.25M per-edge device-scope
// outdeg atomics cost ~25us (partition 42->64us at SAME grid) and ~40MB of
// WRITE_SIZE (atomics execute at the coherence point, ~32B/txn — per-XCD L2
// is non-coherent). Block count was nearly free (65.7 vs 64.4 at 512 vs 153).
// So R15:
//   1) restore streamB/curB/convertB (R12's B-side) — degrees via sequential
//      byte stream + 256-bin LDS hist, no global atomics;
//   2) keep 512 blocks (EPB=2442, ~2/CU) — partition is latency-bound
//      (VALUBusy 1.4%, Occ 12%), and grid size measured ~free;
//   3) vectorize convertB's convert phase (float4/ushort4; R12's was scalar
//      4B/2B per lane — Common-mistake #2).
// Predicted: partition ~28-40us, convertB ~8-12us, total ~140-150.
// Pipeline: memset(curA+curB, 4KB) -> partition -> convertB -> sortgather.

#define GC_D 64
#define PSIZE 196     // nodes per partition: ceil(100000/511); 511 ~ 2*256 CUs
#define SCAP 3072     // stream slots per partition (mean 2450, +12 sigma)
#define EPB 2442      // edges per block: 512 blocks ~ 2/CU (grid ~free, R13/R14)
#define MAXPART 512
#define GC_CAP 64     // fallback-A bucket capacity

// ---------------- main-path kernels ----------------

__global__ __launch_bounds__(512) void partition_kernel(
        const int* __restrict__ src,
        const int* __restrict__ dst,
        int* __restrict__ curA,                 // [nPart] cursors (dst-keyed)
        int* __restrict__ curB,                 // [nPart] cursors (src-keyed)
        int* __restrict__ streamA,              // [nPart*SCAP] s | (d%PSIZE)<<17
        unsigned char* __restrict__ streamB,    // [nPart*SCAP] s%PSIZE
        int e, int nPart) {
    __shared__ int histA[MAXPART], histB[MAXPART], baseA[MAXPART], baseB[MAXPART];
    __shared__ int lcurA[MAXPART], lcurB[MAXPART];
    int t = threadIdx.x;
    for (int i = t; i < nPart; i += 512) {
        histA[i] = 0; histB[i] = 0; lcurA[i] = 0; lcurB[i] = 0;
    }
    __syncthreads();
    int lo = blockIdx.x * EPB;
    int hi = min(lo + EPB, e);
    for (int i = lo + t; i < hi; i += 512) {
        int s = src[i], d = dst[i];
        atomicAdd(&histA[d / PSIZE], 1);
        atomicAdd(&histB[s / PSIZE], 1);
    }
    __syncthreads();
    for (int i = t; i < nPart; i += 512) {
        int hA = histA[i];
        baseA[i] = hA ? atomicAdd(&curA[i], hA) : 0;
        int hB = histB[i];
        baseB[i] = hB ? atomicAdd(&curB[i], hB) : 0;
    }
    __syncthreads();
    for (int i = lo + t; i < hi; i += 512) {
        int s = src[i], d = dst[i];
        int pA = d / PSIZE;                      // compile-time magic div
        int posA = baseA[pA] + atomicAdd(&lcurA[pA], 1);
        if (posA < SCAP) streamA[pA * SCAP + posA] = s | ((d - pA * PSIZE) << 17);
        int pB = s / PSIZE;
        int posB = baseB[pB] + atomicAdd(&lcurB[pB], 1);
        if (posB < SCAP) streamB[pB * SCAP + posB] = (unsigned char)(s - pB * PSIZE);
    }
}

__device__ __forceinline__ unsigned short to_bf16_rne(float v) {
    unsigned b = __float_as_uint(v);
    b = (b + 0x7FFFu + ((b >> 16) & 1u)) >> 16;   // RNE to bf16
    return (unsigned short)b;
}

// One block per partition: outdeg hist from streamB (256-bin LDS), then
// VECTORIZED premultiplied bf16 convert of this partition's PSIZE rows
// (float4 in / ushort4 out per lane). featb row n = zeros (pad target).
__global__ __launch_bounds__(512) void convertB_kernel(
        const int* __restrict__ curB,
        const unsigned char* __restrict__ streamB,
        const float* __restrict__ feat,
        unsigned short* __restrict__ featb,
        int n) {
    __shared__ int lodeg[256];
    __shared__ float lnl[256];
    int p = blockIdx.x, t = threadIdx.x;
    if (t < 256) lodeg[t] = 0;
    __syncthreads();
    int cB = min(curB[p], SCAP);
    const unsigned char* sB = streamB + (size_t)p * SCAP;
    for (int i = t; i < cB; i += 512) atomicAdd(&lodeg[sB[i]], 1);
    __syncthreads();
    if (t < 256) lnl[t] = rsqrtf(fmaxf((float)lodeg[t], 1.0f) + 1.0f);
    __syncthreads();
    int g = p * PSIZE;
    // PSIZE*16 float4-quads per partition; q>>4 monotone in q so break is safe
    for (int q = t; q < PSIZE * 16; q += 512) {
        int r = q >> 4;
        int node = g + r;
        if (node >= n) break;
        float nl = lnl[r];
        size_t base = (size_t)node * GC_D + (q & 15) * 4;
        const float4 v = *(const float4*)(feat + base);
        ushort4 rr;
        rr.x = to_bf16_rne(v.x * nl);
        rr.y = to_bf16_rne(v.y * nl);
        rr.z = to_bf16_rne(v.z * nl);
        rr.w = to_bf16_rne(v.w * nl);
        *(ushort4*)(featb + base) = rr;
    }
    if (p == 0 && t < GC_D) featb[(size_t)n * GC_D + t] = 0;
}

// One 1024-thread block per partition (~2 blocks/CU, balanced). Drain streamA
// into LDS, LDS counting sort into lperm, 16 waves gather one node at a time
// (R9's proven pattern: compiler overlaps independent r-iterations).
__global__ __launch_bounds__(1024) void sortgather_kernel(
        const int* __restrict__ curA,
        const int* __restrict__ streamA,
        const float* __restrict__ feat,
        const unsigned short* __restrict__ featb,
        float* __restrict__ out,
        int n) {
    __shared__ int sAl[SCAP];       // 12 KB staged stream
    __shared__ int lperm[SCAP];     // 12 KB sorted src ids
    __shared__ int lcnt[256], loff[256], lcur[256];
    int p = blockIdx.x, t = threadIdx.x;
    if (t < 256) lcnt[t] = 0;
    __syncthreads();
    int cA = min(curA[p], SCAP);
    const int* sA = streamA + (size_t)p * SCAP;
    for (int i = t; i < cA; i += 1024) {
        int v = sA[i];
        sAl[i] = v;
        atomicAdd(&lcnt[(v >> 17) & 255], 1);
    }
    __syncthreads();
    // exclusive scan of 256 bins (Hillis-Steele on first 256 threads)
    if (t < 256) loff[t] = lcnt[t];
    __syncthreads();
    for (int off = 1; off < 256; off <<= 1) {
        int a = (t < 256 && t >= off) ? loff[t - off] : 0;
        __syncthreads();
        if (t < 256) loff[t] += a;
        __syncthreads();
    }
    if (t < 256) { loff[t] -= lcnt[t]; lcur[t] = 0; }   // exclusive
    __syncthreads();
    for (int i = t; i < cA; i += 1024) {
        int v = sAl[i];
        int bin = (v >> 17) & 255;
        int pos = loff[bin] + atomicAdd(&lcur[bin], 1);
        lperm[pos] = v & 0x1FFFF;
    }
    __syncthreads();
    // gather: wave w handles nodes w, w+16, ...
    int wave = t >> 6, lane = t & 63;
    int half = lane >> 5;      // 0: even edges, 1: odd edges
    int c = lane & 31;         // feature-pair index
    int g = p * PSIZE;
    for (int r = wave; r < PSIZE; r += 16) {
        int node = g + r;
        if (node >= n) break;
        int deg = lcnt[r];
        int off = loff[r];
        float acc0 = 0.0f, acc1 = 0.0f;
        for (int base = 0; base < deg; base += 64) {
            int m = min(deg - base, 64);
            int s_l = (lane < m) ? lperm[off + base + lane] : n;
            int m16 = (m + 15) & ~15;
            for (int j = 0; j < m16; j += 16) {
#pragma unroll
                for (int k = 0; k < 8; ++k) {
                    int s = __shfl(s_l, j + 2 * k + half);
                    unsigned u = *(const unsigned*)(featb + (size_t)s * GC_D + 2 * c);
                    acc0 += __uint_as_float(u << 16);
                    acc1 += __uint_as_float(u & 0xFFFF0000u);
                }
            }
        }
        acc0 += __shfl_xor(acc0, 32);
        acc1 += __shfl_xor(acc1, 32);
        if (half == 0) {
            float nr = rsqrtf(fmaxf((float)deg, 1.0f) + 1.0f);
            const float2 self = *(const float2*)(feat + (size_t)node * GC_D + 2 * c);
            float2 rr;
            rr.x = (self.x + acc0) * nr;
            rr.y = (self.y + acc1) * nr;
            *(float2*)(out + (size_t)node * GC_D + 2 * c) = rr;
        }
    }
}

// ---------------- fallback A (atomic-bucket path, R4-style) ----------------

__global__ void zero_int_kernel(int* __restrict__ p, int n) {
    int i = blockIdx.x * blockDim.x + threadIdx.x;
    if (i < n) p[i] = 0;
}

__global__ void bucket_hist_kernel(const int* __restrict__ src,
                                   const int* __restrict__ dst,
                                   int* __restrict__ cnt,
                                   int* __restrict__ outdeg,
                                   int* __restrict__ bucket,
                                   int e) {
    int i = blockIdx.x * blockDim.x + threadIdx.x;
    if (i < e) {
        int s = src[i];
        int d = dst[i];
        atomicAdd(&outdeg[s], 1);
        int pos = atomicAdd(&cnt[d], 1);
        if (pos < GC_CAP) bucket[d * GC_CAP + pos] = s;
    }
}

__global__ __launch_bounds__(256) void convert_kernel(
        const float* __restrict__ feat,
        const int* __restrict__ outdeg,
        unsigned short* __restrict__ featb,
        int n) {
    int i = blockIdx.x * 256 + threadIdx.x;   // float4 / ushort4 index
    int row = i >> 4;
    if (row > n) return;
    if (row == n) {
        ushort4 z; z.x = 0; z.y = 0; z.z = 0; z.w = 0;
        *(ushort4*)(featb + (size_t)i * 4) = z;
        return;
    }
    float nl = rsqrtf(fmaxf((float)outdeg[row], 1.0f) + 1.0f);
    float4 v = *(const float4*)(feat + (size_t)i * 4);
    ushort4 r;
    r.x = to_bf16_rne(v.x * nl);
    r.y = to_bf16_rne(v.y * nl);
    r.z = to_bf16_rne(v.z * nl);
    r.w = to_bf16_rne(v.w * nl);
    *(ushort4*)(featb + (size_t)i * 4) = r;
}

__global__ __launch_bounds__(256) void gather_bf16_kernel(
        const float* __restrict__ feat,
        const unsigned short* __restrict__ featb,
        const int* __restrict__ bucket,
        const int* __restrict__ cnt,
        float* __restrict__ out,
        int n) {
    int wid = (blockIdx.x * blockDim.x + threadIdx.x) >> 6;
    int lane = threadIdx.x & 63;
    if (wid >= n) return;
    int deg = cnt[wid];
    int s_raw = bucket[wid * GC_CAP + lane];
    int m = min(deg, GC_CAP);
    int s_l = (lane < m) ? s_raw : n;
    int half = lane >> 5;
    int c = lane & 31;
    float acc0 = 0.0f, acc1 = 0.0f;
    int m16 = (m + 15) & ~15;
    for (int j = 0; j < m16; j += 16) {
#pragma unroll
        for (int k = 0; k < 8; ++k) {
            int s = __shfl(s_l, j + 2 * k + half);
            unsigned u = *(const unsigned*)(featb + (size_t)s * GC_D + 2 * c);
            acc0 += __uint_as_float(u << 16);
            acc1 += __uint_as_float(u & 0xFFFF0000u);
        }
    }
    acc0 += __shfl_xor(acc0, 32);
    acc1 += __shfl_xor(acc1, 32);
    if (half == 0) {
        float nr = rsqrtf(fmaxf((float)deg, 1.0f) + 1.0f);
        const float2 self = *(const float2*)(feat + (size_t)wid * GC_D + 2 * c);
        float2 r;
        r.x = (self.x + acc0) * nr;
        r.y = (self.y + acc1) * nr;
        *(float2*)(out + (size_t)wid * GC_D + 2 * c) = r;
    }
}

// ---------------- launch ----------------

extern "C" void kernel_launch(void* const* d_in, const int* in_sizes, int n_in,
                              void* d_out, int out_size, void* d_ws, size_t ws_size,
                              hipStream_t stream) {
    const float* feat = (const float*)d_in[0];
    const int*   src  = (const int*)d_in[1];
    const int*   dst  = (const int*)d_in[2];
    float* out = (float*)d_out;

    const int n = in_sizes[0] / GC_D;   // 100000
    const int e = in_sizes[1];          // 1250000
    const int nPart = (n + PSIZE - 1) / PSIZE;    // 511 for n=100000

    // Main ws layout (int units): curA[nPart] curB[nPart] pad32 ->
    //   streamA[nPart*SCAP] -> featb[(n+1)*64 u16] -> streamB[nPart*SCAP u8]
    size_t featb_ints = ((size_t)(n + 1) * GC_D + 1) / 2;
    size_t o = 2 * (size_t)nPart;
    o = (o + 31) & ~(size_t)31;          // 128B-align streamA (and featb below)
    size_t streamA_o = o;  o += (size_t)nPart * SCAP;
    size_t featb_o = o;    o += featb_ints;
    size_t need_main = o * sizeof(int) + (size_t)nPart * SCAP;   // + streamB u8

    size_t featb_bytes = (size_t)(n + 1) * GC_D * sizeof(unsigned short);
    size_t need_bf16 = ((size_t)2 * n + (size_t)n * GC_CAP) * sizeof(int) + featb_bytes;

    bool main_ok = (ws_size >= need_main) && nPart <= MAXPART && n <= 131071;

    if (main_ok) {
        int* ws = (int*)d_ws;
        int* curA = ws;
        int* curB = ws + nPart;
        int* streamA = ws + streamA_o;
        unsigned short* featb = (unsigned short*)(ws + featb_o);
        unsigned char* streamB = (unsigned char*)(ws + o);

        hipMemsetAsync(curA, 0, 2 * (size_t)nPart * sizeof(int), stream);
        partition_kernel<<<(e + EPB - 1) / EPB, 512, 0, stream>>>(
            src, dst, curA, curB, streamA, streamB, e, nPart);
        convertB_kernel<<<nPart, 512, 0, stream>>>(curB, streamB, feat, featb, n);
        sortgather_kernel<<<nPart, 1024, 0, stream>>>(curA, streamA, feat, featb,
                                                      out, n);
    } else if (ws_size >= need_bf16) {
        int* cnt    = (int*)d_ws;
        int* outdeg = cnt + n;
        int* bucket = outdeg + n;
        unsigned short* featb = (unsigned short*)(bucket + (size_t)n * GC_CAP);

        zero_int_kernel<<<(2 * n + 255) / 256, 256, 0, stream>>>(cnt, 2 * n);
        bucket_hist_kernel<<<(e + 255) / 256, 256, 0, stream>>>(src, dst, cnt,
                                                                outdeg, bucket, e);
        int conv_threads = (n + 1) * 16;
        convert_kernel<<<(conv_threads + 255) / 256, 256, 0, stream>>>(
            feat, outdeg, featb, n);
        long long total = (long long)n * GC_D;
        gather_bf16_kernel<<<(int)((total + 255) / 256), 256, 0, stream>>>(
            feat, featb, bucket, cnt, out, n);
    }
}

// Round 9
// 147.779 us; speedup vs baseline: 1.2404x; 1.0543x over previous
//
#include <hip/hip_runtime.h>

// GraphConv (DGL norm='both', implicit self-loop), N=100000, D=64, E=1250000.
// R17 (2nd resubmit — rounds 7 & 8 hit GPUAcquisitionTimeout, never measured).
// R16 crashed (core dump — device fault OR infra; indistinguishable).
// R16 had 3 changes; crash suspects were the new vector-memory patterns
// (int4 LDS store in sortgather: __shared__ int[] only guarantees 4B align;
// int4 global loads of src/dst: unverified 16B base alignment).
// R17 = R15 (proven 155.8us, passed) + ONLY the partition register-batch:
//   each thread owns 8 consecutive edges, loads them via 2x int4 per array
//   (guarded by a runtime 16B-alignment check, scalar fallback), does hist
//   from registers, REUSES registers in scatter (no 2nd global read pass).
// Theory: partition ~40us in every config = unhidden scalar-load->LDS-atomic
// latency chain run twice over the edge list; batching amortizes load
// latency 8x and halves edge reads.
// Predicted: partition ~40 -> 15-22us, FETCH ~halves, total -> ~135-145.
// Pre-committed: crash again -> resubmit R15 verbatim to disambiguate infra;
// total unchanged -> partition not latency-bound, pivot to gaps/fusion.

#define GC_D 64
#define PSIZE 196     // nodes per partition: ceil(100000/511); 511 ~ 2*256 CUs
#define SCAP 3072     // stream slots per partition (mean 2450, +12 sigma)
#define EPT 8         // edges per thread (2x int4 per edge array)
#define EPB (512*EPT) // 4096 edges per block: 306 blocks
#define MAXPART 512
#define GC_CAP 64     // fallback-A bucket capacity

// ---------------- main-path kernels ----------------

__global__ __launch_bounds__(512) void partition_kernel(
        const int* __restrict__ src,
        const int* __restrict__ dst,
        int* __restrict__ curA,                 // [nPart] cursors (dst-keyed)
        int* __restrict__ curB,                 // [nPart] cursors (src-keyed)
        int* __restrict__ streamA,              // [nPart*SCAP] s | (d%PSIZE)<<17
        unsigned char* __restrict__ streamB,    // [nPart*SCAP] s%PSIZE
        int e, int nPart) {
    __shared__ int histA[MAXPART], histB[MAXPART], baseA[MAXPART], baseB[MAXPART];
    __shared__ int lcurA[MAXPART], lcurB[MAXPART];
    int t = threadIdx.x;
    for (int i = t; i < nPart; i += 512) {
        histA[i] = 0; histB[i] = 0; lcurA[i] = 0; lcurB[i] = 0;
    }
    __syncthreads();
    int base_i = blockIdx.x * EPB + t * EPT;
    int se[EPT], de[EPT];
    bool aligned16 = ((((size_t)src) | ((size_t)dst)) & 15) == 0;
    if (aligned16 && base_i + EPT <= e) {
        // fast path: 2x int4 per array (base_i multiple of 8 -> 32B offset)
        int4 s0 = *(const int4*)(src + base_i);
        int4 s1 = *(const int4*)(src + base_i + 4);
        int4 d0 = *(const int4*)(dst + base_i);
        int4 d1 = *(const int4*)(dst + base_i + 4);
        se[0]=s0.x; se[1]=s0.y; se[2]=s0.z; se[3]=s0.w;
        se[4]=s1.x; se[5]=s1.y; se[6]=s1.z; se[7]=s1.w;
        de[0]=d0.x; de[1]=d0.y; de[2]=d0.z; de[3]=d0.w;
        de[4]=d1.x; de[5]=d1.y; de[6]=d1.z; de[7]=d1.w;
#pragma unroll
        for (int k = 0; k < EPT; ++k) {
            atomicAdd(&histA[de[k] / PSIZE], 1);
            atomicAdd(&histB[se[k] / PSIZE], 1);
        }
    } else {
#pragma unroll
        for (int k = 0; k < EPT; ++k) {
            int i = base_i + k;
            se[k] = 0; de[k] = 0;
            if (i < e) {
                se[k] = src[i]; de[k] = dst[i];
                atomicAdd(&histA[de[k] / PSIZE], 1);
                atomicAdd(&histB[se[k] / PSIZE], 1);
            }
        }
    }
    __syncthreads();
    for (int i = t; i < nPart; i += 512) {
        int hA = histA[i];
        baseA[i] = hA ? atomicAdd(&curA[i], hA) : 0;
        int hB = histB[i];
        baseB[i] = hB ? atomicAdd(&curB[i], hB) : 0;
    }
    __syncthreads();
#pragma unroll
    for (int k = 0; k < EPT; ++k) {
        int i = base_i + k;
        if (i < e) {
            int s = se[k], d = de[k];
            int pA = d / PSIZE;                  // compile-time magic div
            int posA = baseA[pA] + atomicAdd(&lcurA[pA], 1);
            if (posA < SCAP) streamA[pA * SCAP + posA] = s | ((d - pA * PSIZE) << 17);
            int pB = s / PSIZE;
            int posB = baseB[pB] + atomicAdd(&lcurB[pB], 1);
            if (posB < SCAP) streamB[pB * SCAP + posB] = (unsigned char)(s - pB * PSIZE);
        }
    }
}

__device__ __forceinline__ unsigned short to_bf16_rne(float v) {
    unsigned b = __float_as_uint(v);
    b = (b + 0x7FFFu + ((b >> 16) & 1u)) >> 16;   // RNE to bf16
    return (unsigned short)b;
}

// One block per partition: outdeg hist from streamB (256-bin LDS), then
// VECTORIZED premultiplied bf16 convert of this partition's PSIZE rows
// (float4 in / ushort4 out per lane). featb row n = zeros (pad target).
// (byte-exact R15 version — proven)
__global__ __launch_bounds__(512) void convertB_kernel(
        const int* __restrict__ curB,
        const unsigned char* __restrict__ streamB,
        const float* __restrict__ feat,
        unsigned short* __restrict__ featb,
        int n) {
    __shared__ int lodeg[256];
    __shared__ float lnl[256];
    int p = blockIdx.x, t = threadIdx.x;
    if (t < 256) lodeg[t] = 0;
    __syncthreads();
    int cB = min(curB[p], SCAP);
    const unsigned char* sB = streamB + (size_t)p * SCAP;
    for (int i = t; i < cB; i += 512) atomicAdd(&lodeg[sB[i]], 1);
    __syncthreads();
    if (t < 256) lnl[t] = rsqrtf(fmaxf((float)lodeg[t], 1.0f) + 1.0f);
    __syncthreads();
    int g = p * PSIZE;
    // PSIZE*16 float4-quads per partition; q>>4 monotone in q so break is safe
    for (int q = t; q < PSIZE * 16; q += 512) {
        int r = q >> 4;
        int node = g + r;
        if (node >= n) break;
        float nl = lnl[r];
        size_t base = (size_t)node * GC_D + (q & 15) * 4;
        const float4 v = *(const float4*)(feat + base);
        ushort4 rr;
        rr.x = to_bf16_rne(v.x * nl);
        rr.y = to_bf16_rne(v.y * nl);
        rr.z = to_bf16_rne(v.z * nl);
        rr.w = to_bf16_rne(v.w * nl);
        *(ushort4*)(featb + base) = rr;
    }
    if (p == 0 && t < GC_D) featb[(size_t)n * GC_D + t] = 0;
}

// One 1024-thread block per partition (~2 blocks/CU, balanced). Drain streamA
// into LDS, LDS counting sort into lperm, 16 waves gather one node at a time
// (R9's proven pattern; byte-exact R15 version).
__global__ __launch_bounds__(1024) void sortgather_kernel(
        const int* __restrict__ curA,
        const int* __restrict__ streamA,
        const float* __restrict__ feat,
        const unsigned short* __restrict__ featb,
        float* __restrict__ out,
        int n) {
    __shared__ int sAl[SCAP];       // 12 KB staged stream
    __shared__ int lperm[SCAP];     // 12 KB sorted src ids
    __shared__ int lcnt[256], loff[256], lcur[256];
    int p = blockIdx.x, t = threadIdx.x;
    if (t < 256) lcnt[t] = 0;
    __syncthreads();
    int cA = min(curA[p], SCAP);
    const int* sA = streamA + (size_t)p * SCAP;
    for (int i = t; i < cA; i += 1024) {
        int v = sA[i];
        sAl[i] = v;
        atomicAdd(&lcnt[(v >> 17) & 255], 1);
    }
    __syncthreads();
    // exclusive scan of 256 bins (Hillis-Steele on first 256 threads)
    if (t < 256) loff[t] = lcnt[t];
    __syncthreads();
    for (int off = 1; off < 256; off <<= 1) {
        int a = (t < 256 && t >= off) ? loff[t - off] : 0;
        __syncthreads();
        if (t < 256) loff[t] += a;
        __syncthreads();
    }
    if (t < 256) { loff[t] -= lcnt[t]; lcur[t] = 0; }   // exclusive
    __syncthreads();
    for (int i = t; i < cA; i += 1024) {
        int v = sAl[i];
        int bin = (v >> 17) & 255;
        int pos = loff[bin] + atomicAdd(&lcur[bin], 1);
        lperm[pos] = v & 0x1FFFF;
    }
    __syncthreads();
    // gather: wave w handles nodes w, w+16, ...
    int wave = t >> 6, lane = t & 63;
    int half = lane >> 5;      // 0: even edges, 1: odd edges
    int c = lane & 31;         // feature-pair index
    int g = p * PSIZE;
    for (int r = wave; r < PSIZE; r += 16) {
        int node = g + r;
        if (node >= n) break;
        int deg = lcnt[r];
        int off = loff[r];
        float acc0 = 0.0f, acc1 = 0.0f;
        for (int base = 0; base < deg; base += 64) {
            int m = min(deg - base, 64);
            int s_l = (lane < m) ? lperm[off + base + lane] : n;
            int m16 = (m + 15) & ~15;
            for (int j = 0; j < m16; j += 16) {
#pragma unroll
                for (int k = 0; k < 8; ++k) {
                    int s = __shfl(s_l, j + 2 * k + half);
                    unsigned u = *(const unsigned*)(featb + (size_t)s * GC_D + 2 * c);
                    acc0 += __uint_as_float(u << 16);
                    acc1 += __uint_as_float(u & 0xFFFF0000u);
                }
            }
        }
        acc0 += __shfl_xor(acc0, 32);
        acc1 += __shfl_xor(acc1, 32);
        if (half == 0) {
            float nr = rsqrtf(fmaxf((float)deg, 1.0f) + 1.0f);
            const float2 self = *(const float2*)(feat + (size_t)node * GC_D + 2 * c);
            float2 rr;
            rr.x = (self.x + acc0) * nr;
            rr.y = (self.y + acc1) * nr;
            *(float2*)(out + (size_t)node * GC_D + 2 * c) = rr;
        }
    }
}

// ---------------- fallback A (atomic-bucket path, R4-style) ----------------

__global__ void zero_int_kernel(int* __restrict__ p, int n) {
    int i = blockIdx.x * blockDim.x + threadIdx.x;
    if (i < n) p[i] = 0;
}

__global__ void bucket_hist_kernel(const int* __restrict__ src,
                                   const int* __restrict__ dst,
                                   int* __restrict__ cnt,
                                   int* __restrict__ outdeg,
                                   int* __restrict__ bucket,
                                   int e) {
    int i = blockIdx.x * blockDim.x + threadIdx.x;
    if (i < e) {
        int s = src[i];
        int d = dst[i];
        atomicAdd(&outdeg[s], 1);
        int pos = atomicAdd(&cnt[d], 1);
        if (pos < GC_CAP) bucket[d * GC_CAP + pos] = s;
    }
}

__global__ __launch_bounds__(256) void convert_kernel(
        const float* __restrict__ feat,
        const int* __restrict__ outdeg,
        unsigned short* __restrict__ featb,
        int n) {
    int i = blockIdx.x * 256 + threadIdx.x;   // float4 / ushort4 index
    int row = i >> 4;
    if (row > n) return;
    if (row == n) {
        ushort4 z; z.x = 0; z.y = 0; z.z = 0; z.w = 0;
        *(ushort4*)(featb + (size_t)i * 4) = z;
        return;
    }
    float nl = rsqrtf(fmaxf((float)outdeg[row], 1.0f) + 1.0f);
    float4 v = *(const float4*)(feat + (size_t)i * 4);
    ushort4 r;
    r.x = to_bf16_rne(v.x * nl);
    r.y = to_bf16_rne(v.y * nl);
    r.z = to_bf16_rne(v.z * nl);
    r.w = to_bf16_rne(v.w * nl);
    *(ushort4*)(featb + (size_t)i * 4) = r;
}

__global__ __launch_bounds__(256) void gather_bf16_kernel(
        const float* __restrict__ feat,
        const unsigned short* __restrict__ featb,
        const int* __restrict__ bucket,
        const int* __restrict__ cnt,
        float* __restrict__ out,
        int n) {
    int wid = (blockIdx.x * blockDim.x + threadIdx.x) >> 6;
    int lane = threadIdx.x & 63;
    if (wid >= n) return;
    int deg = cnt[wid];
    int s_raw = bucket[wid * GC_CAP + lane];
    int m = min(deg, GC_CAP);
    int s_l = (lane < m) ? s_raw : n;
    int half = lane >> 5;
    int c = lane & 31;
    float acc0 = 0.0f, acc1 = 0.0f;
    int m16 = (m + 15) & ~15;
    for (int j = 0; j < m16; j += 16) {
#pragma unroll
        for (int k = 0; k < 8; ++k) {
            int s = __shfl(s_l, j + 2 * k + half);
            unsigned u = *(const unsigned*)(featb + (size_t)s * GC_D + 2 * c);
            acc0 += __uint_as_float(u << 16);
            acc1 += __uint_as_float(u & 0xFFFF0000u);
        }
    }
    acc0 += __shfl_xor(acc0, 32);
    acc1 += __shfl_xor(acc1, 32);
    if (half == 0) {
        float nr = rsqrtf(fmaxf((float)deg, 1.0f) + 1.0f);
        const float2 self = *(const float2*)(feat + (size_t)wid * GC_D + 2 * c);
        float2 r;
        r.x = (self.x + acc0) * nr;
        r.y = (self.y + acc1) * nr;
        *(float2*)(out + (size_t)wid * GC_D + 2 * c) = r;
    }
}

// ---------------- launch ----------------

extern "C" void kernel_launch(void* const* d_in, const int* in_sizes, int n_in,
                              void* d_out, int out_size, void* d_ws, size_t ws_size,
                              hipStream_t stream) {
    const float* feat = (const float*)d_in[0];
    const int*   src  = (const int*)d_in[1];
    const int*   dst  = (const int*)d_in[2];
    float* out = (float*)d_out;

    const int n = in_sizes[0] / GC_D;   // 100000
    const int e = in_sizes[1];          // 1250000
    const int nPart = (n + PSIZE - 1) / PSIZE;    // 511 for n=100000

    // Main ws layout (int units): curA[nPart] curB[nPart] pad32 ->
    //   streamA[nPart*SCAP] -> featb[(n+1)*64 u16] -> streamB[nPart*SCAP u8]
    size_t featb_ints = ((size_t)(n + 1) * GC_D + 1) / 2;
    size_t o = 2 * (size_t)nPart;
    o = (o + 31) & ~(size_t)31;          // 128B-align streamA (and featb below)
    size_t streamA_o = o;  o += (size_t)nPart * SCAP;
    size_t featb_o = o;    o += featb_ints;
    size_t need_main = o * sizeof(int) + (size_t)nPart * SCAP;   // + streamB u8

    size_t featb_bytes = (size_t)(n + 1) * GC_D * sizeof(unsigned short);
    size_t need_bf16 = ((size_t)2 * n + (size_t)n * GC_CAP) * sizeof(int) + featb_bytes;

    bool main_ok = (ws_size >= need_main) && nPart <= MAXPART && n <= 131071;

    if (main_ok) {
        int* ws = (int*)d_ws;
        int* curA = ws;
        int* curB = ws + nPart;
        int* streamA = ws + streamA_o;
        unsigned short* featb = (unsigned short*)(ws + featb_o);
        unsigned char* streamB = (unsigned char*)(ws + o);

        hipMemsetAsync(curA, 0, 2 * (size_t)nPart * sizeof(int), stream);
        partition_kernel<<<(e + EPB - 1) / EPB, 512, 0, stream>>>(
            src, dst, curA, curB, streamA, streamB, e, nPart);
        convertB_kernel<<<nPart, 512, 0, stream>>>(curB, streamB, feat, featb, n);
        sortgather_kernel<<<nPart, 1024, 0, stream>>>(curA, streamA, feat, featb,
                                                      out, n);
    } else if (ws_size >= need_bf16) {
        int* cnt    = (int*)d_ws;
        int* outdeg = cnt + n;
        int* bucket = outdeg + n;
        unsigned short* featb = (unsigned short*)(bucket + (size_t)n * GC_CAP);

        zero_int_kernel<<<(2 * n + 255) / 256, 256, 0, stream>>>(cnt, 2 * n);
        bucket_hist_kernel<<<(e + 255) / 256, 256, 0, stream>>>(src, dst, cnt,
                                                                outdeg, bucket, e);
        int conv_threads = (n + 1) * 16;
        convert_kernel<<<(conv_threads + 255) / 256, 256, 0, stream>>>(
            feat, outdeg, featb, n);
        long long total = (long long)n * GC_D;
        gather_bf16_kernel<<<(int)((total + 255) / 256), 256, 0, stream>>>(
            feat, featb, bucket, cnt, out, n);
    }
}